// Round 15
// baseline (934.334 us; speedup 1.0000x reference)
//
#include <hip/hip_runtime.h>
#include <hip/hip_bf16.h>

#define N_NODES   50000
#define N_EDGES   800000
#define D         256
#define N_LAYERS  3
#define N_GRAPHS  64
#define LN_EPS    1e-5f
#define NB_SCAN   ((N_NODES + 255) / 256)   // 196
#define XT_THREADS (N_NODES * D / 8)        // 1.6M
#define NCHUNK    1563                      // ceil(12500 agg-units / 8)

typedef __attribute__((ext_vector_type(8))) short bf16x8;
typedef __attribute__((ext_vector_type(4))) float f32x4;

__device__ __forceinline__ unsigned short f2bf(float f) {
    unsigned int u = __float_as_uint(f);
    unsigned int r = (u + 0x7FFFu + ((u >> 16) & 1u)) >> 16;
    return (unsigned short)r;
}
__device__ __forceinline__ float bf2f(unsigned short h) {
    return __uint_as_float(((unsigned int)h) << 16);
}

// LLC-coherent 16B store/load (bypass non-coherent per-XCD L2 for the
// intra-kernel aggx handoff; h/W keep normal cached paths)
__device__ __forceinline__ void store_b128_sc(void* addr, bf16x8 v) {
    asm volatile("global_store_dwordx4 %0, %1, off sc0 sc1" :: "v"(addr), "v"(v) : "memory");
}
__device__ __forceinline__ bf16x8 load_b128_sc(const void* addr) {
    bf16x8 r;
    asm volatile("global_load_dwordx4 %0, %1, off sc0 sc1" : "=v"(r) : "v"(addr) : "memory");
    return r;
}

// ---------------------------------------------------------------------------
// merged: x (fp32) -> bf16 scaled by dinv[row]  AND  W -> Wbt transpose
__global__ void k_convert(const float* __restrict__ x, const float* __restrict__ dinv,
                          unsigned short* __restrict__ xb,
                          const float* __restrict__ W, unsigned short* __restrict__ Wbt) {
    int gid = blockIdx.x * blockDim.x + threadIdx.x;
    if (gid < XT_THREADS) {
        int base = gid * 8;
        float sc = dinv[base >> 8];
        const float4* x4 = (const float4*)(x + base);
        float4 a = x4[0], b = x4[1];
        ushort4 lo, hi;
        lo.x = f2bf(a.x * sc); lo.y = f2bf(a.y * sc); lo.z = f2bf(a.z * sc); lo.w = f2bf(a.w * sc);
        hi.x = f2bf(b.x * sc); hi.y = f2bf(b.y * sc); hi.z = f2bf(b.z * sc); hi.w = f2bf(b.w * sc);
        ((ushort4*)(xb + base))[0] = lo;
        ((ushort4*)(xb + base))[1] = hi;
    } else {
        int g2 = gid - XT_THREADS;
        if (g2 < N_LAYERS * D * D) {
            int l = g2 >> 16;
            int rem = g2 & 65535;
            int n = rem >> 8;
            int k = rem & 255;
            Wbt[(size_t)l * D * D + n * D + k] = f2bf(W[(size_t)l * D * D + k * D + n]);
        }
    }
}

// ---------------------------------------------------------------------------
__global__ void k_indeg(const int* __restrict__ dst, int* __restrict__ indeg) {
    int e = blockIdx.x * blockDim.x + threadIdx.x;
    if (e < N_EDGES) atomicAdd(&indeg[dst[e]], 1);
}

__global__ __launch_bounds__(256) void k_dinv_bsum(const int* __restrict__ indeg,
                                                   float* __restrict__ dinv,
                                                   int* __restrict__ bsum) {
    int b = blockIdx.x, t = threadIdx.x;
    int i = b * 256 + t;
    int v = (i < N_NODES) ? indeg[i] : 0;
    if (i < N_NODES) dinv[i] = rsqrtf((float)(v + 1));
    int s = v;
#pragma unroll
    for (int m = 32; m >= 1; m >>= 1) s += __shfl_xor(s, m);
    __shared__ int sh[4];
    if ((t & 63) == 0) sh[t >> 6] = s;
    __syncthreads();
    if (t == 0) bsum[b] = sh[0] + sh[1] + sh[2] + sh[3];
}

__global__ __launch_bounds__(256) void k_bscan_counts(const int* __restrict__ bsum,
                                                      int* __restrict__ bbase,
                                                      const int* __restrict__ batch,
                                                      int* __restrict__ counts) {
    int t = threadIdx.x;
    if (t < N_GRAPHS) {
        int g = t;
        int lo = 0, hi = N_NODES;
        while (lo < hi) { int mid = (lo + hi) >> 1; if (batch[mid] < g) lo = mid + 1; else hi = mid; }
        int start = lo;
        lo = 0; hi = N_NODES;
        int g1 = g + 1;
        while (lo < hi) { int mid = (lo + hi) >> 1; if (batch[mid] < g1) lo = mid + 1; else hi = mid; }
        counts[g] = lo - start;
    }
    __shared__ int s[256];
    int v = (t < NB_SCAN) ? bsum[t] : 0;
    s[t] = v;
    __syncthreads();
    for (int off = 1; off < 256; off <<= 1) {
        int tv = (t >= off) ? s[t - off] : 0;
        __syncthreads();
        s[t] += tv;
        __syncthreads();
    }
    if (t < NB_SCAN) bbase[t] = s[t] - v;
}

__global__ __launch_bounds__(256) void k_offsets(const int* __restrict__ indeg, const int* __restrict__ bbase,
                                                 int* __restrict__ offsets, int* __restrict__ cursor) {
    __shared__ int s[256];
    int b = blockIdx.x, t = threadIdx.x;
    int i = b * 256 + t;
    int v = (i < N_NODES) ? indeg[i] : 0;
    s[t] = v;
    __syncthreads();
    for (int off = 1; off < 256; off <<= 1) {
        int tv = (t >= off) ? s[t - off] : 0;
        __syncthreads();
        s[t] += tv;
        __syncthreads();
    }
    if (i < N_NODES) {
        int o = bbase[b] + s[t] - v;
        offsets[i] = o;
        cursor[i]  = o;
    }
}

__global__ void k_csr_fill(const int* __restrict__ src, const int* __restrict__ dst,
                           int* __restrict__ cursor, unsigned short* __restrict__ esrc) {
    int e = blockIdx.x * blockDim.x + threadIdx.x;
    if (e >= N_EDGES) return;
    int s = src[e], d = dst[e];
    int pos = atomicAdd(&cursor[d], 1);
    esrc[pos] = (unsigned short)s;
}

// ---------------------------------------------------------------------------
// Producer/consumer layer: grid = NCHUNK chunks x 9 blocks.
// slot 0..7: agg unit u = chunk*8+slot (4 nodes, 1 per wave) -> aggx via
//            LLC-coherent stores -> vmcnt(0) -> ready[chunk]++ (device atomic).
// slot 8:    gemm block for rows chunk*32..+31: spins on ready[chunk]==8,
//            reads aggx via LLC-coherent loads, W/bias cached; bias+LN+ReLU;
//            writes hOut with normal stores (inter-kernel visibility).
// Deadlock-safe: 1563 spinners < 2048 worst-case resident blocks (256thr,8w/EU).
__global__ __launch_bounds__(256, 8) void k_layer_pc(const unsigned short* __restrict__ hs,
                                                     const int* __restrict__ offsets,
                                                     const int* __restrict__ indeg,
                                                     const float* __restrict__ dinv,
                                                     const unsigned short* __restrict__ esrc,
                                                     unsigned short* __restrict__ aggx,
                                                     int* __restrict__ ready,
                                                     const unsigned short* __restrict__ Wbt,
                                                     const float* __restrict__ bias,
                                                     const float* __restrict__ gamma,
                                                     const float* __restrict__ beta,
                                                     const float* __restrict__ rowscale,
                                                     unsigned short* __restrict__ out) {
    const int chunk = blockIdx.x / 9;
    const int slot  = blockIdx.x - chunk * 9;
    const int t = threadIdx.x;
    const int lane = t & 63;

    if (slot < 8) {
        // ---------------- agg role ----------------
        const int u = chunk * 8 + slot;            // agg unit (4 nodes)
        const int node = u * 4 + (t >> 6);
        if (u < 12500 && node < N_NODES) {
            const int hw = lane >> 5;
            const int dl = lane & 31;
            const unsigned short* hp = hs + dl * 8;

            float acc[8];
            if (hw == 0) {
                bf16x8 v = *(const bf16x8*)(hp + (size_t)node * 256);
#pragma unroll
                for (int j = 0; j < 8; ++j) acc[j] = bf2f((unsigned short)v[j]);
            } else {
#pragma unroll
                for (int j = 0; j < 8; ++j) acc[j] = 0.f;
            }

            const int beg = offsets[node];
            const int end = beg + indeg[node];
            int i = beg + hw;
            for (; i + 6 < end; i += 8) {
                int s0 = esrc[i];
                int s1 = esrc[i + 2];
                int s2 = esrc[i + 4];
                int s3 = esrc[i + 6];
                bf16x8 v0 = *(const bf16x8*)(hp + (size_t)s0 * 256);
                bf16x8 v1 = *(const bf16x8*)(hp + (size_t)s1 * 256);
                bf16x8 v2 = *(const bf16x8*)(hp + (size_t)s2 * 256);
                bf16x8 v3 = *(const bf16x8*)(hp + (size_t)s3 * 256);
#pragma unroll
                for (int j = 0; j < 8; ++j) acc[j] += bf2f((unsigned short)v0[j]);
#pragma unroll
                for (int j = 0; j < 8; ++j) acc[j] += bf2f((unsigned short)v1[j]);
#pragma unroll
                for (int j = 0; j < 8; ++j) acc[j] += bf2f((unsigned short)v2[j]);
#pragma unroll
                for (int j = 0; j < 8; ++j) acc[j] += bf2f((unsigned short)v3[j]);
            }
            for (; i < end; i += 2) {
                int s0 = esrc[i];
                bf16x8 v0 = *(const bf16x8*)(hp + (size_t)s0 * 256);
#pragma unroll
                for (int j = 0; j < 8; ++j) acc[j] += bf2f((unsigned short)v0[j]);
            }

#pragma unroll
            for (int j = 0; j < 8; ++j) acc[j] += __shfl_xor(acc[j], 32);

            if (hw == 0) {
                float sc = dinv[node];
                bf16x8 o;
#pragma unroll
                for (int j = 0; j < 8; ++j) o[j] = (short)f2bf(acc[j] * sc);
                store_b128_sc(aggx + (size_t)node * 256 + dl * 8, o);
            }
        }
        // completion: drain stores, then signal
        asm volatile("s_waitcnt vmcnt(0)" ::: "memory");
        __syncthreads();
        if (t == 0) atomicAdd(&ready[chunk], 1);
    } else {
        // ---------------- gemm role (32 rows) ----------------
        __shared__ float red[2][4][32];
        const int w = t >> 6;
        const int lrow = lane & 15;
        const int q = lane >> 4;
        const int mbase = chunk * 32;
        const int ncb = w * 64;

        if (t == 0) {
            while (atomicAdd(&ready[chunk], 0) < 8) __builtin_amdgcn_s_sleep(8);
        }
        __syncthreads();

        int rowA[2];
#pragma unroll
        for (int mt = 0; mt < 2; ++mt) {
            int r = mbase + mt * 16 + lrow;
            rowA[mt] = (r < N_NODES) ? r : (N_NODES - 1);
        }
        const unsigned short* a0 = aggx + (size_t)rowA[0] * 256 + q * 8;
        const unsigned short* a1 = aggx + (size_t)rowA[1] * 256 + q * 8;
        const unsigned short* wp = Wbt + (size_t)(ncb + lrow) * 256 + q * 8;

        f32x4 acc[2][4];
#pragma unroll
        for (int mt = 0; mt < 2; ++mt)
#pragma unroll
            for (int nt = 0; nt < 4; ++nt) acc[mt][nt] = (f32x4){0.f, 0.f, 0.f, 0.f};

#pragma unroll
        for (int kk = 0; kk < 8; ++kk) {
            bf16x8 av0 = load_b128_sc(a0 + kk * 32);
            bf16x8 av1 = load_b128_sc(a1 + kk * 32);
            bf16x8 bw[4];
#pragma unroll
            for (int nt = 0; nt < 4; ++nt)
                bw[nt] = *(const bf16x8*)(wp + (size_t)nt * 16 * 256 + kk * 32);
            asm volatile("s_waitcnt vmcnt(0)" ::: "memory");
            __builtin_amdgcn_sched_barrier(0);
#pragma unroll
            for (int nt = 0; nt < 4; ++nt) {
                acc[0][nt] = __builtin_amdgcn_mfma_f32_16x16x32_bf16(bw[nt], av0, acc[0][nt], 0, 0, 0);
                acc[1][nt] = __builtin_amdgcn_mfma_f32_16x16x32_bf16(bw[nt], av1, acc[1][nt], 0, 0, 0);
            }
        }

        const float4* bias4 = (const float4*)bias;
#pragma unroll
        for (int mt = 0; mt < 2; ++mt) {
            float s = 0.f, s2 = 0.f;
#pragma unroll
            for (int nt = 0; nt < 4; ++nt) {
                float4 bv = bias4[w * 16 + nt * 4 + q];
#pragma unroll
                for (int r = 0; r < 4; ++r) {
                    float v = acc[mt][nt][r] + ((const float*)&bv)[r];
                    acc[mt][nt][r] = v;
                    s += v;
                    s2 += v * v;
                }
            }
            s  += __shfl_xor(s, 16);  s  += __shfl_xor(s, 32);
            s2 += __shfl_xor(s2, 16); s2 += __shfl_xor(s2, 32);
            if (lane < 16) {
                red[0][w][mt * 16 + lane] = s;
                red[1][w][mt * 16 + lane] = s2;
            }
        }
        __syncthreads();

        const float4* g4 = (const float4*)gamma;
        const float4* be4 = (const float4*)beta;
#pragma unroll
        for (int mt = 0; mt < 2; ++mt) {
            int r = mt * 16 + lrow;
            float s = 0.f, s2 = 0.f;
#pragma unroll
            for (int j = 0; j < 4; ++j) { s += red[0][j][r]; s2 += red[1][j][r]; }
            float mu = s * (1.0f / 256.0f);
            float var = s2 * (1.0f / 256.0f) - mu * mu;
            float rs = rsqrtf(var + LN_EPS);

            int row = mbase + r;
            if (row < N_NODES) {
                float sc = (rowscale != nullptr) ? rowscale[row] : 1.0f;
#pragma unroll
                for (int nt = 0; nt < 4; ++nt) {
                    float4 gv = g4[w * 16 + nt * 4 + q];
                    float4 bev = be4[w * 16 + nt * 4 + q];
                    ushort4 o;
                    float v0 = fmaxf((acc[mt][nt][0] - mu) * rs * gv.x + bev.x, 0.f) * sc;
                    float v1 = fmaxf((acc[mt][nt][1] - mu) * rs * gv.y + bev.y, 0.f) * sc;
                    float v2 = fmaxf((acc[mt][nt][2] - mu) * rs * gv.z + bev.z, 0.f) * sc;
                    float v3 = fmaxf((acc[mt][nt][3] - mu) * rs * gv.w + bev.w, 0.f) * sc;
                    o.x = f2bf(v0); o.y = f2bf(v1); o.z = f2bf(v2); o.w = f2bf(v3);
                    *(ushort4*)(out + (size_t)row * 256 + ncb + nt * 16 + q * 4) = o;
                }
            }
        }
    }
}

// ---------------------------------------------------------------------------
__global__ __launch_bounds__(256) void k_pool(const unsigned short* __restrict__ h,
                                              const int* __restrict__ batch,
                                              float* __restrict__ sums) {
    __shared__ int sb[128];
    int t = threadIdx.x;
    int n0 = blockIdx.x * 128;
    int cnt = N_NODES - n0; if (cnt > 128) cnt = 128;
    if (cnt <= 0) return;
    if (t < cnt) sb[t] = batch[n0 + t];
    __syncthreads();

    float acc = 0.f;
    int g = sb[0];
    for (int i = 0; i < cnt; ++i) {
        int bg = sb[i];
        if (bg != g) {
            atomicAdd(&sums[g * 256 + t], acc);
            acc = 0.f;
            g = bg;
        }
        acc += bf2f(h[(size_t)(n0 + i) * 256 + t]);
    }
    atomicAdd(&sums[g * 256 + t], acc);
}

__global__ void k_finalize(const float* __restrict__ sums, const int* __restrict__ counts,
                           float* __restrict__ out) {
    int idx = blockIdx.x * blockDim.x + threadIdx.x;
    if (idx < N_GRAPHS * 256) {
        float c = (float)counts[idx >> 8];
        out[idx] = sums[idx] / fmaxf(c, 1.f);
    }
}

// ---------------------------------------------------------------------------
extern "C" void kernel_launch(void* const* d_in, const int* in_sizes, int n_in,
                              void* d_out, int out_size, void* d_ws, size_t ws_size,
                              hipStream_t stream) {
    const float* x     = (const float*)d_in[0];
    const int*   ei    = (const int*)d_in[1];
    const int*   batch = (const int*)d_in[2];
    const float* Ws    = (const float*)d_in[3];
    const float* bs    = (const float*)d_in[4];
    const float* gammas= (const float*)d_in[5];
    const float* betas = (const float*)d_in[6];
    float* out = (float*)d_out;

    const int* src = ei;
    const int* dst = ei + N_EDGES;

    char* p = (char*)d_ws;
    unsigned short* hbfA  = (unsigned short*)p; p += (size_t)N_NODES * D * 2;   // 25.6 MB
    unsigned short* hbfB  = (unsigned short*)p; p += (size_t)N_NODES * D * 2;   // 25.6 MB
    unsigned short* aggx  = (unsigned short*)p; p += (size_t)N_NODES * D * 2;   // 25.6 MB
    unsigned short* Wbt   = (unsigned short*)p; p += (size_t)N_LAYERS * D * D * 2;
    int*   indeg  = (int*)p;   p += (size_t)N_NODES * 4;
    int*   offs   = (int*)p;   p += (size_t)N_NODES * 4;
    int*   cursor = (int*)p;   p += (size_t)N_NODES * 4;
    float* dinv   = (float*)p; p += (size_t)N_NODES * 4;
    int*   bsum   = (int*)p;   p += (size_t)NB_SCAN * 4;
    int*   bbase  = (int*)p;   p += (size_t)NB_SCAN * 4;
    unsigned short* esrc = (unsigned short*)p; p += (size_t)N_EDGES * 2;
    float* sums   = (float*)p; p += (size_t)N_GRAPHS * D * 4;
    int*   counts = (int*)p;   p += (size_t)N_GRAPHS * 4;
    int*   ready3 = (int*)p;   p += (size_t)3 * NCHUNK * 4;

    hipMemsetAsync(indeg, 0, (size_t)N_NODES * 4, stream);
    hipMemsetAsync(sums, 0, (size_t)N_GRAPHS * D * 4, stream);
    hipMemsetAsync(ready3, 0, (size_t)3 * NCHUNK * 4, stream);

    // graph preprocessing
    k_indeg <<<(N_EDGES + 255) / 256, 256, 0, stream>>>(dst, indeg);
    k_dinv_bsum<<<NB_SCAN, 256, 0, stream>>>(indeg, dinv, bsum);
    k_convert<<<(XT_THREADS + N_LAYERS * D * D + 255) / 256, 256, 0, stream>>>(x, dinv, hbfA, Ws, Wbt);
    k_bscan_counts<<<1, 256, 0, stream>>>(bsum, bbase, batch, counts);
    k_offsets<<<NB_SCAN, 256, 0, stream>>>(indeg, bbase, offs, cursor);
    k_csr_fill<<<(N_EDGES + 255) / 256, 256, 0, stream>>>(src, dst, cursor, esrc);

    // 3 producer/consumer GCN layers (aggregate-first; hs = dinv*h between layers)
    const int pc_grid = NCHUNK * 9;   // 14067 blocks
    unsigned short* bufs[2] = {hbfA, hbfB};
    for (int l = 0; l < N_LAYERS; ++l) {
        const unsigned short* in_h = bufs[l & 1];
        unsigned short* out_h      = bufs[(l + 1) & 1];
        const float* rsc = (l == N_LAYERS - 1) ? nullptr : dinv;
        k_layer_pc<<<pc_grid, 256, 0, stream>>>(in_h, offs, indeg, dinv, esrc,
                                                aggx, ready3 + l * NCHUNK,
                                                Wbt + (size_t)l * D * D,
                                                bs + (size_t)l * D,
                                                gammas + (size_t)l * D,
                                                betas + (size_t)l * D, rsc, out_h);
    }

    // global mean pool (last layer wrote unscaled h into hbfB)
    unsigned short* hfin = bufs[N_LAYERS & 1];
    k_pool<<<(N_NODES + 127) / 128, 256, 0, stream>>>(hfin, batch, sums);
    k_finalize<<<(N_GRAPHS * 256 + 255) / 256, 256, 0, stream>>>(sums, counts, out);
}

// Round 16
// 424.563 us; speedup vs baseline: 2.2007x; 2.2007x over previous
//
#include <hip/hip_runtime.h>
#include <hip/hip_bf16.h>
#include <hip/hip_fp16.h>

#define N_NODES   50000
#define N_EDGES   800000
#define D         256
#define N_LAYERS  3
#define N_GRAPHS  64
#define LN_EPS    1e-5f
#define NB_SCAN   ((N_NODES + 255) / 256)   // 196
#define XT_THREADS (N_NODES * D / 8)        // 1.6M

typedef __attribute__((ext_vector_type(8))) short bf16x8;
typedef __attribute__((ext_vector_type(4))) float f32x4;

__device__ __forceinline__ unsigned short f2bf(float f) {
    unsigned int u = __float_as_uint(f);
    unsigned int r = (u + 0x7FFFu + ((u >> 16) & 1u)) >> 16;
    return (unsigned short)r;
}
__device__ __forceinline__ float bf2f(unsigned short h) {
    return __uint_as_float(((unsigned int)h) << 16);
}

// fp8 e4m3 <-> f32 via exact f16 bit-embedding:
// e4m3 bits<<7 is the f16 of (value * 2^-8), subnormals included.
// The 2^8 decode factor is folded into the caller's final scale.
__device__ __forceinline__ float f8tof_s(unsigned int b) {   // returns value * 2^-8
    unsigned short h = (unsigned short)(((b & 0x80u) << 8) | ((b & 0x7fu) << 7));
    return __half2float(__ushort_as_half(h));
}
__device__ __forceinline__ unsigned int ftof8(float v) {     // v >= 0 (post-ReLU)
    v = fminf(v, 448.f);
    unsigned short hb = __half_as_ushort(__float2half(v * 0.00390625f));  // * 2^-8
    hb = (unsigned short)(hb + 0x3F + ((hb >> 7) & 1));                   // RNE to 3-bit mantissa
    return (unsigned int)((hb >> 7) & 0x7fu);
}

// ---------------------------------------------------------------------------
// merged: x (fp32) -> bf16 scaled by dinv[row]  AND  W -> Wbt transpose
__global__ void k_convert(const float* __restrict__ x, const float* __restrict__ dinv,
                          unsigned short* __restrict__ xb,
                          const float* __restrict__ W, unsigned short* __restrict__ Wbt) {
    int gid = blockIdx.x * blockDim.x + threadIdx.x;
    if (gid < XT_THREADS) {
        int base = gid * 8;
        float sc = dinv[base >> 8];
        const float4* x4 = (const float4*)(x + base);
        float4 a = x4[0], b = x4[1];
        ushort4 lo, hi;
        lo.x = f2bf(a.x * sc); lo.y = f2bf(a.y * sc); lo.z = f2bf(a.z * sc); lo.w = f2bf(a.w * sc);
        hi.x = f2bf(b.x * sc); hi.y = f2bf(b.y * sc); hi.z = f2bf(b.z * sc); hi.w = f2bf(b.w * sc);
        ((ushort4*)(xb + base))[0] = lo;
        ((ushort4*)(xb + base))[1] = hi;
    } else {
        int g2 = gid - XT_THREADS;
        if (g2 < N_LAYERS * D * D) {
            int l = g2 >> 16;
            int rem = g2 & 65535;
            int n = rem >> 8;
            int k = rem & 255;
            Wbt[(size_t)l * D * D + n * D + k] = f2bf(W[(size_t)l * D * D + k * D + n]);
        }
    }
}

// ---------------------------------------------------------------------------
__global__ void k_indeg(const int* __restrict__ dst, int* __restrict__ indeg) {
    int e = blockIdx.x * blockDim.x + threadIdx.x;
    if (e < N_EDGES) atomicAdd(&indeg[dst[e]], 1);
}

__global__ __launch_bounds__(256) void k_dinv_bsum(const int* __restrict__ indeg,
                                                   float* __restrict__ dinv,
                                                   int* __restrict__ bsum) {
    int b = blockIdx.x, t = threadIdx.x;
    int i = b * 256 + t;
    int v = (i < N_NODES) ? indeg[i] : 0;
    if (i < N_NODES) dinv[i] = rsqrtf((float)(v + 1));
    int s = v;
#pragma unroll
    for (int m = 32; m >= 1; m >>= 1) s += __shfl_xor(s, m);
    __shared__ int sh[4];
    if ((t & 63) == 0) sh[t >> 6] = s;
    __syncthreads();
    if (t == 0) bsum[b] = sh[0] + sh[1] + sh[2] + sh[3];
}

__global__ __launch_bounds__(256) void k_bscan_counts(const int* __restrict__ bsum,
                                                      int* __restrict__ bbase,
                                                      const int* __restrict__ batch,
                                                      int* __restrict__ counts) {
    int t = threadIdx.x;
    if (t < N_GRAPHS) {
        int g = t;
        int lo = 0, hi = N_NODES;
        while (lo < hi) { int mid = (lo + hi) >> 1; if (batch[mid] < g) lo = mid + 1; else hi = mid; }
        int start = lo;
        lo = 0; hi = N_NODES;
        int g1 = g + 1;
        while (lo < hi) { int mid = (lo + hi) >> 1; if (batch[mid] < g1) lo = mid + 1; else hi = mid; }
        counts[g] = lo - start;
    }
    __shared__ int s[256];
    int v = (t < NB_SCAN) ? bsum[t] : 0;
    s[t] = v;
    __syncthreads();
    for (int off = 1; off < 256; off <<= 1) {
        int tv = (t >= off) ? s[t - off] : 0;
        __syncthreads();
        s[t] += tv;
        __syncthreads();
    }
    if (t < NB_SCAN) bbase[t] = s[t] - v;
}

__global__ __launch_bounds__(256) void k_offsets(const int* __restrict__ indeg, const int* __restrict__ bbase,
                                                 int* __restrict__ offsets, int* __restrict__ cursor) {
    __shared__ int s[256];
    int b = blockIdx.x, t = threadIdx.x;
    int i = b * 256 + t;
    int v = (i < N_NODES) ? indeg[i] : 0;
    s[t] = v;
    __syncthreads();
    for (int off = 1; off < 256; off <<= 1) {
        int tv = (t >= off) ? s[t - off] : 0;
        __syncthreads();
        s[t] += tv;
        __syncthreads();
    }
    if (i < N_NODES) {
        int o = bbase[b] + s[t] - v;
        offsets[i] = o;
        cursor[i]  = o;
    }
}

__global__ void k_csr_fill(const int* __restrict__ src, const int* __restrict__ dst,
                           int* __restrict__ cursor, unsigned short* __restrict__ esrc) {
    int e = blockIdx.x * blockDim.x + threadIdx.x;
    if (e >= N_EDGES) return;
    int s = src[e], d = dst[e];
    int pos = atomicAdd(&cursor[d], 1);
    esrc[pos] = (unsigned short)s;
}

// ---------------------------------------------------------------------------
// bf16 aggregate (layer 0): agg[n] = dinv[n] * (hs[n] + sum_edges hs[src])
__global__ __launch_bounds__(256) void k_agg(const unsigned short* __restrict__ h,
                                             const int* __restrict__ offsets,
                                             const int* __restrict__ indeg,
                                             const float* __restrict__ dinv,
                                             const unsigned short* __restrict__ esrc,
                                             unsigned short* __restrict__ outA) {
    const int node = blockIdx.x * 4 + (threadIdx.x >> 6);
    const int lane = threadIdx.x & 63;
    if (node >= N_NODES) return;
    const int hw = lane >> 5;
    const int dl = lane & 31;
    const unsigned short* hp = h + dl * 8;

    float acc[8];
    if (hw == 0) {
        bf16x8 v = *(const bf16x8*)(hp + (size_t)node * 256);
#pragma unroll
        for (int j = 0; j < 8; ++j) acc[j] = bf2f((unsigned short)v[j]);
    } else {
#pragma unroll
        for (int j = 0; j < 8; ++j) acc[j] = 0.f;
    }

    const int beg = offsets[node];
    const int end = beg + indeg[node];
    int i = beg + hw;
    for (; i + 6 < end; i += 8) {
        int s0 = esrc[i];
        int s1 = esrc[i + 2];
        int s2 = esrc[i + 4];
        int s3 = esrc[i + 6];
        bf16x8 v0 = *(const bf16x8*)(hp + (size_t)s0 * 256);
        bf16x8 v1 = *(const bf16x8*)(hp + (size_t)s1 * 256);
        bf16x8 v2 = *(const bf16x8*)(hp + (size_t)s2 * 256);
        bf16x8 v3 = *(const bf16x8*)(hp + (size_t)s3 * 256);
#pragma unroll
        for (int j = 0; j < 8; ++j) acc[j] += bf2f((unsigned short)v0[j]);
#pragma unroll
        for (int j = 0; j < 8; ++j) acc[j] += bf2f((unsigned short)v1[j]);
#pragma unroll
        for (int j = 0; j < 8; ++j) acc[j] += bf2f((unsigned short)v2[j]);
#pragma unroll
        for (int j = 0; j < 8; ++j) acc[j] += bf2f((unsigned short)v3[j]);
    }
    for (; i < end; i += 2) {
        int s0 = esrc[i];
        bf16x8 v0 = *(const bf16x8*)(hp + (size_t)s0 * 256);
#pragma unroll
        for (int j = 0; j < 8; ++j) acc[j] += bf2f((unsigned short)v0[j]);
    }

#pragma unroll
    for (int j = 0; j < 8; ++j) acc[j] += __shfl_xor(acc[j], 32);

    if (hw == 0) {
        float sc = dinv[node];
        bf16x8 o;
#pragma unroll
        for (int j = 0; j < 8; ++j) o[j] = (short)f2bf(acc[j] * sc);
        *(bf16x8*)(outA + (size_t)node * 256 + dl * 8) = o;
    }
}

// fp8 aggregate (layers 1,2): rows are 256 B; half-wave = 32 lanes x 8 B.
// Decoded values carry a uniform 2^-8 factor, folded into the final scale.
__device__ __forceinline__ void f8acc(uint2 d, float* acc) {
#pragma unroll
    for (int j = 0; j < 4; ++j) acc[j]     += f8tof_s((d.x >> (8 * j)) & 0xffu);
#pragma unroll
    for (int j = 0; j < 4; ++j) acc[4 + j] += f8tof_s((d.y >> (8 * j)) & 0xffu);
}

__global__ __launch_bounds__(256) void k_agg_f8(const unsigned char* __restrict__ h8,
                                                const int* __restrict__ offsets,
                                                const int* __restrict__ indeg,
                                                const float* __restrict__ dinv,
                                                const unsigned short* __restrict__ esrc,
                                                unsigned short* __restrict__ outA) {
    const int node = blockIdx.x * 4 + (threadIdx.x >> 6);
    const int lane = threadIdx.x & 63;
    if (node >= N_NODES) return;
    const int hw = lane >> 5;
    const int dl = lane & 31;
    const unsigned char* hp = h8 + dl * 8;

    float acc[8];
#pragma unroll
    for (int j = 0; j < 8; ++j) acc[j] = 0.f;
    if (hw == 0) {
        uint2 d = *(const uint2*)(hp + (size_t)node * 256);
        f8acc(d, acc);
    }

    const int beg = offsets[node];
    const int end = beg + indeg[node];
    int i = beg + hw;
    for (; i + 6 < end; i += 8) {
        int s0 = esrc[i];
        int s1 = esrc[i + 2];
        int s2 = esrc[i + 4];
        int s3 = esrc[i + 6];
        uint2 d0 = *(const uint2*)(hp + (size_t)s0 * 256);
        uint2 d1 = *(const uint2*)(hp + (size_t)s1 * 256);
        uint2 d2 = *(const uint2*)(hp + (size_t)s2 * 256);
        uint2 d3 = *(const uint2*)(hp + (size_t)s3 * 256);
        f8acc(d0, acc);
        f8acc(d1, acc);
        f8acc(d2, acc);
        f8acc(d3, acc);
    }
    for (; i < end; i += 2) {
        int s0 = esrc[i];
        uint2 d0 = *(const uint2*)(hp + (size_t)s0 * 256);
        f8acc(d0, acc);
    }

#pragma unroll
    for (int j = 0; j < 8; ++j) acc[j] += __shfl_xor(acc[j], 32);

    if (hw == 0) {
        float sc = dinv[node] * 256.0f;   // undo the 2^-8 decode factor
        bf16x8 o;
#pragma unroll
        for (int j = 0; j < 8; ++j) o[j] = (short)f2bf(acc[j] * sc);
        *(bf16x8*)(outA + (size_t)node * 256 + dl * 8) = o;
    }
}

// ---------------------------------------------------------------------------
// fused GEMM + bias + LayerNorm + ReLU (round-10 proven structure).
// MODE 0: out = fp8(relu(LN)*dinv)  (hidden layers)
// MODE 1: out = bf16(relu(LN))      (last layer, for pooling)
template<int MODE>
__global__ __launch_bounds__(512, 4) void k_gemm_ln(const unsigned short* __restrict__ A,
                                                    const unsigned short* __restrict__ Wbt,
                                                    const float* __restrict__ bias,
                                                    const float* __restrict__ gamma,
                                                    const float* __restrict__ beta,
                                                    const float* __restrict__ rowscale,
                                                    unsigned short* __restrict__ outb,
                                                    unsigned char* __restrict__ out8) {
    __shared__ short alds[64 * 256];      // 32 KB swizzled A-tile
    __shared__ float red[2][8][64];       // 4 KB LN partials
    const int t = threadIdx.x;
    const int lane = t & 63;
    const int w = t >> 6;                 // wave 0..7
    const int lrow = lane & 15;
    const int q = lane >> 4;              // 0..3
    const int ncb = w * 32;               // wave's column base
    const int brow = blockIdx.x * 64;

    // stage A tile: coalesced global read, swizzled ds_write
#pragma unroll
    for (int it = 0; it < 4; ++it) {
        int L = it * 512 + t;
        int r = L >> 5;
        int c = L & 31;
        int row = brow + r; if (row >= N_NODES) row = N_NODES - 1;
        bf16x8 v = *(const bf16x8*)(A + (size_t)row * 256 + c * 8);
        *(bf16x8*)(alds + r * 256 + (c ^ (r & 7)) * 8) = v;
    }
    __syncthreads();

    f32x4 acc[4][2];
#pragma unroll
    for (int mt = 0; mt < 4; ++mt)
#pragma unroll
        for (int nt = 0; nt < 2; ++nt) acc[mt][nt] = (f32x4){0.f, 0.f, 0.f, 0.f};

    const unsigned short* wp0 = Wbt + (size_t)(ncb + lrow) * 256 + q * 8;
    const unsigned short* wp1 = Wbt + (size_t)(ncb + 16 + lrow) * 256 + q * 8;

#pragma unroll
    for (int kh = 0; kh < 2; ++kh) {
        bf16x8 wf0[4], wf1[4];
#pragma unroll
        for (int ks = 0; ks < 4; ++ks) {
            wf0[ks] = *(const bf16x8*)(wp0 + (kh * 4 + ks) * 32);
            wf1[ks] = *(const bf16x8*)(wp1 + (kh * 4 + ks) * 32);
        }
#pragma unroll
        for (int ks = 0; ks < 4; ++ks) {
            int kk = kh * 4 + ks;
            int cs = (kk * 4 + q) ^ (lrow & 7);
#pragma unroll
            for (int mt = 0; mt < 4; ++mt) {
                bf16x8 av = *(const bf16x8*)(alds + (mt * 16 + lrow) * 256 + cs * 8);
                acc[mt][0] = __builtin_amdgcn_mfma_f32_16x16x32_bf16(wf0[ks], av, acc[mt][0], 0, 0, 0);
                acc[mt][1] = __builtin_amdgcn_mfma_f32_16x16x32_bf16(wf1[ks], av, acc[mt][1], 0, 0, 0);
            }
        }
    }

    const float4* bias4 = (const float4*)bias;
#pragma unroll
    for (int mt = 0; mt < 4; ++mt) {
        float s = 0.f, s2 = 0.f;
#pragma unroll
        for (int nt = 0; nt < 2; ++nt) {
            float4 bv = bias4[w * 8 + nt * 4 + q];
#pragma unroll
            for (int r = 0; r < 4; ++r) {
                float v = acc[mt][nt][r] + ((const float*)&bv)[r];
                acc[mt][nt][r] = v;
                s += v;
                s2 += v * v;
            }
        }
        s  += __shfl_xor(s, 16);  s  += __shfl_xor(s, 32);
        s2 += __shfl_xor(s2, 16); s2 += __shfl_xor(s2, 32);
        if (lane < 16) {
            red[0][w][mt * 16 + lane] = s;
            red[1][w][mt * 16 + lane] = s2;
        }
    }
    __syncthreads();

    const float4* g4 = (const float4*)gamma;
    const float4* be4 = (const float4*)beta;
#pragma unroll
    for (int mt = 0; mt < 4; ++mt) {
        int r = mt * 16 + lrow;
        float s = 0.f, s2 = 0.f;
#pragma unroll
        for (int j = 0; j < 8; ++j) { s += red[0][j][r]; s2 += red[1][j][r]; }
        float mu = s * (1.0f / 256.0f);
        float var = s2 * (1.0f / 256.0f) - mu * mu;
        float rs = rsqrtf(var + LN_EPS);

        int row = brow + r;
        if (row < N_NODES) {
#pragma unroll
            for (int nt = 0; nt < 2; ++nt) {
                float4 gv = g4[w * 8 + nt * 4 + q];
                float4 bev = be4[w * 8 + nt * 4 + q];
                float v0 = fmaxf((acc[mt][nt][0] - mu) * rs * gv.x + bev.x, 0.f);
                float v1 = fmaxf((acc[mt][nt][1] - mu) * rs * gv.y + bev.y, 0.f);
                float v2 = fmaxf((acc[mt][nt][2] - mu) * rs * gv.z + bev.z, 0.f);
                float v3 = fmaxf((acc[mt][nt][3] - mu) * rs * gv.w + bev.w, 0.f);
                if (MODE == 0) {
                    float sc = rowscale[row];
                    unsigned int u = ftof8(v0 * sc) | (ftof8(v1 * sc) << 8)
                                   | (ftof8(v2 * sc) << 16) | (ftof8(v3 * sc) << 24);
                    *(unsigned int*)(out8 + (size_t)row * 256 + ncb + nt * 16 + q * 4) = u;
                } else {
                    ushort4 o;
                    o.x = f2bf(v0); o.y = f2bf(v1); o.z = f2bf(v2); o.w = f2bf(v3);
                    *(ushort4*)(outb + (size_t)row * 256 + ncb + nt * 16 + q * 4) = o;
                }
            }
        }
    }
}

// ---------------------------------------------------------------------------
__global__ __launch_bounds__(256) void k_pool(const unsigned short* __restrict__ h,
                                              const int* __restrict__ batch,
                                              float* __restrict__ sums) {
    __shared__ int sb[128];
    int t = threadIdx.x;
    int n0 = blockIdx.x * 128;
    int cnt = N_NODES - n0; if (cnt > 128) cnt = 128;
    if (cnt <= 0) return;
    if (t < cnt) sb[t] = batch[n0 + t];
    __syncthreads();

    float acc = 0.f;
    int g = sb[0];
    for (int i = 0; i < cnt; ++i) {
        int bg = sb[i];
        if (bg != g) {
            atomicAdd(&sums[g * 256 + t], acc);
            acc = 0.f;
            g = bg;
        }
        acc += bf2f(h[(size_t)(n0 + i) * 256 + t]);
    }
    atomicAdd(&sums[g * 256 + t], acc);
}

__global__ void k_finalize(const float* __restrict__ sums, const int* __restrict__ counts,
                           float* __restrict__ out) {
    int idx = blockIdx.x * blockDim.x + threadIdx.x;
    if (idx < N_GRAPHS * 256) {
        float c = (float)counts[idx >> 8];
        out[idx] = sums[idx] / fmaxf(c, 1.f);
    }
}

// ---------------------------------------------------------------------------
extern "C" void kernel_launch(void* const* d_in, const int* in_sizes, int n_in,
                              void* d_out, int out_size, void* d_ws, size_t ws_size,
                              hipStream_t stream) {
    const float* x     = (const float*)d_in[0];
    const int*   ei    = (const int*)d_in[1];
    const int*   batch = (const int*)d_in[2];
    const float* Ws    = (const float*)d_in[3];
    const float* bs    = (const float*)d_in[4];
    const float* gammas= (const float*)d_in[5];
    const float* betas = (const float*)d_in[6];
    float* out = (float*)d_out;

    const int* src = ei;
    const int* dst = ei + N_EDGES;

    char* p = (char*)d_ws;
    unsigned short* hbf   = (unsigned short*)p; p += (size_t)N_NODES * D * 2;   // 25.6 MB (x-bf16 in; final h out)
    unsigned short* aggx  = (unsigned short*)p; p += (size_t)N_NODES * D * 2;   // 25.6 MB
    unsigned char*  h8    = (unsigned char*)p;  p += (size_t)N_NODES * D;       // 12.8 MB fp8 hidden
    unsigned short* Wbt   = (unsigned short*)p; p += (size_t)N_LAYERS * D * D * 2;
    int*   indeg  = (int*)p;   p += (size_t)N_NODES * 4;
    int*   offs   = (int*)p;   p += (size_t)N_NODES * 4;
    int*   cursor = (int*)p;   p += (size_t)N_NODES * 4;
    float* dinv   = (float*)p; p += (size_t)N_NODES * 4;
    int*   bsum   = (int*)p;   p += (size_t)NB_SCAN * 4;
    int*   bbase  = (int*)p;   p += (size_t)NB_SCAN * 4;
    unsigned short* esrc = (unsigned short*)p; p += (size_t)N_EDGES * 2;
    float* sums   = (float*)p; p += (size_t)N_GRAPHS * D * 4;
    int*   counts = (int*)p;   p += (size_t)N_GRAPHS * 4;

    hipMemsetAsync(indeg, 0, (size_t)N_NODES * 4, stream);
    hipMemsetAsync(sums, 0, (size_t)N_GRAPHS * D * 4, stream);

    // graph preprocessing
    k_indeg <<<(N_EDGES + 255) / 256, 256, 0, stream>>>(dst, indeg);
    k_dinv_bsum<<<NB_SCAN, 256, 0, stream>>>(indeg, dinv, bsum);
    k_convert<<<(XT_THREADS + N_LAYERS * D * D + 255) / 256, 256, 0, stream>>>(x, dinv, hbf, Ws, Wbt);
    k_bscan_counts<<<1, 256, 0, stream>>>(bsum, bbase, batch, counts);
    k_offsets<<<NB_SCAN, 256, 0, stream>>>(indeg, bbase, offs, cursor);
    k_csr_fill<<<(N_EDGES + 255) / 256, 256, 0, stream>>>(src, dst, cursor, esrc);

    const int agg_grid  = (N_NODES + 3) / 4;
    const int gemm_grid = (N_NODES + 63) / 64;

    // layer 0: bf16 gather of x; gemm -> fp8 hidden (rowscale = dinv)
    k_agg<<<agg_grid, 256, 0, stream>>>(hbf, offs, indeg, dinv, esrc, aggx);
    k_gemm_ln<0><<<gemm_grid, 512, 0, stream>>>(aggx, Wbt, bs, gammas, betas, dinv, nullptr, h8);

    // layer 1: fp8 gather; gemm -> fp8 hidden
    k_agg_f8<<<agg_grid, 256, 0, stream>>>(h8, offs, indeg, dinv, esrc, aggx);
    k_gemm_ln<0><<<gemm_grid, 512, 0, stream>>>(aggx, Wbt + (size_t)1 * D * D,
                                                bs + 1 * D, gammas + 1 * D, betas + 1 * D,
                                                dinv, nullptr, h8);

    // layer 2: fp8 gather; gemm -> bf16 (no rowscale) for pooling
    k_agg_f8<<<agg_grid, 256, 0, stream>>>(h8, offs, indeg, dinv, esrc, aggx);
    k_gemm_ln<1><<<gemm_grid, 512, 0, stream>>>(aggx, Wbt + (size_t)2 * D * D,
                                                bs + 2 * D, gammas + 2 * D, betas + 2 * D,
                                                nullptr, hbf, nullptr);

    // global mean pool
    k_pool<<<(N_NODES + 127) / 128, 256, 0, stream>>>(hbf, batch, sums);
    k_finalize<<<(N_GRAPHS * 256 + 255) / 256, 256, 0, stream>>>(sums, counts, out);
}